// Round 2
// baseline (152.174 us; speedup 1.0000x reference)
//
#include <hip/hip_runtime.h>

#define KK 121                   // 11*11
#define NPAIR (512 * 512)        // 262,144 (o,i) pairs
#define PPB 64                   // pairs per block
#define NBLK (NPAIR / PPB)       // 4096 blocks
#define F4PB (PPB * KK / 4)      // 1936 float4 of output per block (exact)

typedef float floatx4 __attribute__((ext_vector_type(4)));

// out[p][k] = P_p*x1[k]^2 + Q_p*x2[k]^2 + R_p*x1[k]*x2[k]
//   e1 = exp(-a00), e2 = exp(-a11), f = a10*e2
//   P = e1^2*(1+f^2), Q = e2^2, R = -2*f*e1*e2
//
// Direct-store version: no 31KB LDS staging, no second barrier.
// Each thread materializes its output float4 in registers by decoding
// (p, k) from the flat element index with exact magic-multiply division:
//   p = (f*17333)>>21   (== f/121 for f < 14873; here f < 7744)
//   k = f - 121*p
// LDS: 64x float4 {P,Q,R,-} (1KB) + 121x float4 {x1^2,x2^2,x1x2,-} (1.9KB)
// -> 2.9KB/block, 8 blocks/CU (32 waves) vs 4 before.
__global__ __launch_bounds__(256, 8) void
quad_stream_kernel(const float4* __restrict__ chol4,
                   const float* __restrict__ pg,
                   float4* __restrict__ out4) {
    __shared__ float4 s_pqr[PPB];   // {P,Q,R,0} per pair
    __shared__ float4 s_uvw[KK];    // {x1^2, x2^2, x1*x2, 0} per k

    const int t = threadIdx.x;

    if (t < KK) {
        float x1 = pg[t];
        float x2 = pg[KK + t];
        s_uvw[t] = make_float4(x1 * x1, x2 * x2, x1 * x2, 0.f);
    }
    if (t < PPB) {
        float4 c = chol4[blockIdx.x * PPB + t];   // {a00,a01,a10,a11}
        float e1 = __expf(-c.x);
        float e2 = __expf(-c.w);
        float f  = c.z * e2;
        float P  = e1 * e1 * fmaf(f, f, 1.f);
        float Q  = e2 * e2;
        float R  = -2.f * f * e1 * e2;
        s_pqr[t] = make_float4(P, Q, R, 0.f);
    }
    __syncthreads();

    // Stream out: lane i writes output float4 (blockBase + i). Consecutive
    // lanes -> consecutive 16B -> 1KB/wave-instr, fully coalesced.
    floatx4* o = (floatx4*)(out4 + (size_t)blockIdx.x * F4PB);
#pragma unroll 2
    for (int i = t; i < F4PB; i += 256) {
        const int f0 = 4 * i;
        floatx4 res;
#pragma unroll
        for (int e = 0; e < 4; ++e) {
            const int fe = f0 + e;
            const int p  = (fe * 17333) >> 21;   // fe / 121 (exact here)
            const int k  = fe - 121 * p;         // fe % 121
            const float4 pqr = s_pqr[p];         // ~2-3 distinct addrs/wave
            const float4 uvw = s_uvw[k];         // spread across bank groups
            // identical fma ordering to previous kernel -> bit-identical out
            res[e] = fmaf(pqr.x, uvw.x, fmaf(pqr.y, uvw.y, pqr.z * uvw.z));
        }
        // write-once stream: bypass L2 retention
        __builtin_nontemporal_store(res, &o[i]);
    }
}

extern "C" void kernel_launch(void* const* d_in, const int* in_sizes, int n_in,
                              void* d_out, int out_size, void* d_ws, size_t ws_size,
                              hipStream_t stream) {
    const float4* chol4 = (const float4*)d_in[0];  // (512,512,2,2) fp32
    const float* pg     = (const float*)d_in[1];   // (2,121) fp32
    float4* out4        = (float4*)d_out;          // (512,512,11,11) fp32

    quad_stream_kernel<<<NBLK, 256, 0, stream>>>(chol4, pg, out4);
}

// Round 3
// 131.311 us; speedup vs baseline: 1.1589x; 1.1589x over previous
//
#include <hip/hip_runtime.h>

#define KK 121                   // 11*11
#define NPAIR (512 * 512)        // 262,144 (o,i) pairs
#define PPB 64                   // pairs per block
#define NBLK (NPAIR / PPB)       // 4096 blocks
#define PAIRS_PER_WAVE (PPB / 4) // 16 (4 waves per block)

// out[p][k] = P_p*x1[k]^2 + Q_p*x2[k]^2 + R_p*x1[k]*x2[k]
//   e1 = exp(-a00), e2 = exp(-a11), f = a10*e2
//   P = e1^2*(1+f^2), Q = e2^2, R = -2*f*e1*e2
//
// Lane-owns-k version: lane l keeps {x1^2,x2^2,x1x2} for k=l and k=64+l in
// REGISTERS (read from LDS once). Each wave loops over 16 pairs; per pair:
//   - s_pqr[p] read is wave-uniform -> LDS broadcast, conflict-free
//   - 6 fma + 2 global_store_dword; consecutive lanes write consecutive
//     dwords -> fully coalesced 256B/instr
// Hot loop has ZERO index decode and ZERO non-broadcast LDS traffic.
// LDS: 64 + 121 float4 = 2.9KB -> 8 blocks/CU.
__global__ __launch_bounds__(256, 8) void
quad_lanek_kernel(const float4* __restrict__ chol4,
                  const float* __restrict__ pg,
                  float* __restrict__ out) {
    __shared__ float4 s_pqr[PPB];   // {P,Q,R,0} per pair
    __shared__ float4 s_uvw[KK];    // {x1^2, x2^2, x1*x2, 0} per k

    const int t = threadIdx.x;

    if (t < KK) {
        float x1 = pg[t];
        float x2 = pg[KK + t];
        s_uvw[t] = make_float4(x1 * x1, x2 * x2, x1 * x2, 0.f);
    }
    if (t < PPB) {
        float4 c = chol4[blockIdx.x * PPB + t];   // {a00,a01,a10,a11}
        float e1 = __expf(-c.x);
        float e2 = __expf(-c.w);
        float f  = c.z * e2;
        float P  = e1 * e1 * fmaf(f, f, 1.f);
        float Q  = e2 * e2;
        float R  = -2.f * f * e1 * e2;
        s_pqr[t] = make_float4(P, Q, R, 0.f);
    }
    __syncthreads();

    const int lane = t & 63;
    const int wave = t >> 6;
    const bool hasB = (lane < KK - 64);           // lanes 0..56 own k=64+l too

    // one-time LDS -> register load of this lane's two grid points
    const float4 uvwA = s_uvw[lane];
    const float4 uvwB = s_uvw[hasB ? (64 + lane) : lane];

    float* ob = out + (size_t)blockIdx.x * (PPB * KK);

#pragma unroll
    for (int j = 0; j < PAIRS_PER_WAVE; ++j) {
        const int p = wave * PAIRS_PER_WAVE + j;
        const float4 c = s_pqr[p];                // uniform addr -> broadcast
        // identical fma ordering to previous kernels -> bit-identical out
        const float rA = fmaf(c.x, uvwA.x, fmaf(c.y, uvwA.y, c.z * uvwA.z));
        ob[p * KK + lane] = rA;
        if (hasB) {
            const float rB = fmaf(c.x, uvwB.x, fmaf(c.y, uvwB.y, c.z * uvwB.z));
            ob[p * KK + 64 + lane] = rB;
        }
    }
}

extern "C" void kernel_launch(void* const* d_in, const int* in_sizes, int n_in,
                              void* d_out, int out_size, void* d_ws, size_t ws_size,
                              hipStream_t stream) {
    const float4* chol4 = (const float4*)d_in[0];  // (512,512,2,2) fp32
    const float* pg     = (const float*)d_in[1];   // (2,121) fp32
    float* out          = (float*)d_out;           // (512,512,11,11) fp32

    quad_lanek_kernel<<<NBLK, 256, 0, stream>>>(chol4, pg, out);
}